// Round 1
// baseline (632.333 us; speedup 1.0000x reference)
//
#include <hip/hip_runtime.h>

typedef __attribute__((ext_vector_type(4))) float f32x4;
typedef __attribute__((ext_vector_type(8))) short short8v;
typedef __attribute__((ext_vector_type(2))) unsigned int uint2v;
typedef __attribute__((ext_vector_type(4))) unsigned int uint4v;

static constexpr int Sdim = 2048;
static constexpr int Ddim = 128;
static constexpr int BN   = 64;                      // kv tile
static constexpr float kAlpha0 = 0.08838834764831844f; // 1/sqrt(128)

__device__ __forceinline__ unsigned int bfpack(float a, float b) {
  // round-to-nearest-even f32->bf16, pack two into a dword (lo=a, hi=b)
  unsigned int ua = __builtin_bit_cast(unsigned int, a);
  unsigned int ub = __builtin_bit_cast(unsigned int, b);
  ua = (ua + 0x7FFFu + ((ua >> 16) & 1u)) >> 16;
  ub = (ub + 0x7FFFu + ((ub >> 16) & 1u)) >> 16;
  return (ua & 0xFFFFu) | (ub << 16);
}

__device__ __forceinline__ float fast_sigmoid(float x) {
  return __builtin_amdgcn_rcpf(1.0f + __expf(-x));
}

// S^T = K@Q^T per tile; sigmoid(alpha*S+bias); O += P@V.
// Wave w owns q rows [q0+32w, q0+32w+32). All fragment layouts are the
// verified gfx950 16x16x32 ones: A/B lane l -> (row/col=l&15, k=(l>>4)*8+j),
// C/D lane l -> (n=l&15, m=(l>>4)*4+reg).
__global__ __launch_bounds__(256, 2) void sigattn_kernel(
    const float* __restrict__ Q, const float* __restrict__ K,
    const float* __restrict__ V, const float* __restrict__ Bias,
    float* __restrict__ Out) {
  __shared__ __align__(16) unsigned char ldsK[BN * 256];    // bf16 [kv][128], byte = kv*256 + ((2d)^((kv&7)<<4))
  __shared__ __align__(16) unsigned char ldsV[Ddim * 128];  // bf16 [d][64]^T, byte = d*128 + ((2r)^(vswz(d)<<4))

  const int b    = blockIdx.x;
  const int xcd  = b & 7;       // keep a head's 16 q-blocks on one XCD (L2 reuse of K/V)
  const int jj   = b >> 3;
  const int head = xcd * 3 + (jj >> 4);   // 24 (b,h) heads
  const int q0   = (jj & 15) * 128;

  const int tid   = threadIdx.x;
  const int w     = tid >> 6;
  const int lane  = tid & 63;
  const int g     = lane >> 4;
  const int qlane = lane & 15;

  const float* __restrict__ Qh = Q + (size_t)head * Sdim * Ddim;
  const float* __restrict__ Kh = K + (size_t)head * Sdim * Ddim;
  const float* __restrict__ Vh = V + (size_t)head * Sdim * Ddim;
  const float* __restrict__ Bh = Bias + (size_t)head * Sdim * Sdim;
  float* __restrict__ Oh = Out + (size_t)head * Sdim * Ddim;

  // ---- Q fragments (MFMA B operand), registers for the whole block ----
  short8v qfrag[2][4];
#pragma unroll
  for (int nf = 0; nf < 2; ++nf) {
    const float* qp = Qh + (size_t)(q0 + w * 32 + nf * 16 + qlane) * Ddim;
#pragma unroll
    for (int kf = 0; kf < 4; ++kf) {
      const int d0 = kf * 32 + g * 8;
      f32x4 a = *(const f32x4*)(qp + d0);
      f32x4 c = *(const f32x4*)(qp + d0 + 4);
      uint4v u;
      u[0] = bfpack(a[0], a[1]);
      u[1] = bfpack(a[2], a[3]);
      u[2] = bfpack(c[0], c[1]);
      u[3] = bfpack(c[2], c[3]);
      qfrag[nf][kf] = __builtin_bit_cast(short8v, u);
    }
  }

  const f32x4 fzero = {0.0f, 0.0f, 0.0f, 0.0f};
  f32x4 oacc[2][8];
#pragma unroll
  for (int qf = 0; qf < 2; ++qf)
#pragma unroll
    for (int nd = 0; nd < 8; ++nd) oacc[qf][nd] = fzero;

  // bpermute lane indices for P^T(C/D layout) -> PV A-fragment redistribution
  const int idxA = ((((2 * g) & 3) * 16 + qlane) << 2);
  const int idxB = ((((2 * g + 1) & 3) * 16 + qlane) << 2);
  const bool lowhalf = (lane < 32);

  for (int t = 0; t < Sdim / BN; ++t) {
    const int kv0 = t * BN;

    // ---------- stage K tile (fp32 -> bf16, swizzled row-major) ----------
    {
      const int rb = tid >> 5;
      const int c4 = (tid & 31) * 4;
#pragma unroll
      for (int p = 0; p < 8; ++p) {
        const int r = p * 8 + rb;
        f32x4 kk = *(const f32x4*)(Kh + (size_t)(kv0 + r) * Ddim + c4);
        uint2v u;
        u[0] = bfpack(kk[0], kk[1]);
        u[1] = bfpack(kk[2], kk[3]);
        *(uint2v*)(ldsK + r * 256 + ((c4 * 2) ^ ((r & 7) << 4))) = u;
      }
    }
    // ---------- stage V tile transposed ([d][kv] bf16, swizzled) ----------
#pragma unroll
    for (int hh = 0; hh < 2; ++hh) {
      const int vb = tid + hh * 256;       // 512 4x4 blocks
      const int r0 = (vb >> 5) * 4;        // kv base (coalesced rows)
      const int d4 = (vb & 31) * 4;        // d base
      f32x4 v0 = *(const f32x4*)(Vh + (size_t)(kv0 + r0 + 0) * Ddim + d4);
      f32x4 v1 = *(const f32x4*)(Vh + (size_t)(kv0 + r0 + 1) * Ddim + d4);
      f32x4 v2 = *(const f32x4*)(Vh + (size_t)(kv0 + r0 + 2) * Ddim + d4);
      f32x4 v3 = *(const f32x4*)(Vh + (size_t)(kv0 + r0 + 3) * Ddim + d4);
#pragma unroll
      for (int dd = 0; dd < 4; ++dd) {
        const int d = d4 + dd;
        uint2v u;
        u[0] = bfpack(v0[dd], v1[dd]);
        u[1] = bfpack(v2[dd], v3[dd]);
        *(uint2v*)(ldsV + d * 128 + ((r0 * 2) ^ (((d ^ (d >> 2)) & 7) << 4))) = u;
      }
    }
    __syncthreads();

    // ---------- bias loads in S^T C/D layout (issued before MFMA) ----------
    f32x4 bb[4][2];
#pragma unroll
    for (int mf = 0; mf < 4; ++mf)
#pragma unroll
      for (int nf = 0; nf < 2; ++nf) {
        const int row = q0 + w * 32 + nf * 16 + qlane;
        const int col = kv0 + mf * 16 + g * 4;
        bb[mf][nf] = *(const f32x4*)(Bh + (size_t)row * Sdim + col);
      }

    // ---------- S^T = K @ Q^T ----------
    f32x4 sacc[4][2];
#pragma unroll
    for (int mf = 0; mf < 4; ++mf)
#pragma unroll
      for (int nf = 0; nf < 2; ++nf) sacc[mf][nf] = fzero;
#pragma unroll
    for (int kf = 0; kf < 4; ++kf)
#pragma unroll
      for (int mf = 0; mf < 4; ++mf) {
        const int kv = mf * 16 + qlane;
        const int d0 = kf * 32 + g * 8;
        short8v kf8 = *(const short8v*)(ldsK + kv * 256 + ((d0 * 2) ^ ((kv & 7) << 4)));
#pragma unroll
        for (int nf = 0; nf < 2; ++nf)
          sacc[mf][nf] = __builtin_amdgcn_mfma_f32_16x16x32_bf16(
              kf8, qfrag[nf][kf], sacc[mf][nf], 0, 0, 0);
      }

    // ---------- sigmoid(alpha0*S + bias) -> packed bf16 pairs ----------
    unsigned int pw[4][2][2];
#pragma unroll
    for (int mf = 0; mf < 4; ++mf)
#pragma unroll
      for (int nf = 0; nf < 2; ++nf) {
        float p0 = fast_sigmoid(sacc[mf][nf][0] * kAlpha0 + bb[mf][nf][0]);
        float p1 = fast_sigmoid(sacc[mf][nf][1] * kAlpha0 + bb[mf][nf][1]);
        float p2 = fast_sigmoid(sacc[mf][nf][2] * kAlpha0 + bb[mf][nf][2]);
        float p3 = fast_sigmoid(sacc[mf][nf][3] * kAlpha0 + bb[mf][nf][3]);
        pw[mf][nf][0] = bfpack(p0, p1);
        pw[mf][nf][1] = bfpack(p2, p3);
      }

    // ---------- redistribute P^T (C/D layout) -> PV A-fragments ----------
    // A-frag a covers kv 32a..32a+31: lane group g needs kv=32a+8g+j.
    // j<4 from lane group (2g+0)&3, j>=4 from (2g+1)&3; frag sel by (lane<32).
    short8v pa[2][2];
#pragma unroll
    for (int nf = 0; nf < 2; ++nf)
#pragma unroll
      for (int a = 0; a < 2; ++a) {
        uint4v u;
        int lo, hi;
        lo = __builtin_amdgcn_ds_bpermute(idxA, (int)pw[2 * a][nf][0]);
        hi = __builtin_amdgcn_ds_bpermute(idxA, (int)pw[2 * a + 1][nf][0]);
        u[0] = (unsigned)(lowhalf ? lo : hi);
        lo = __builtin_amdgcn_ds_bpermute(idxA, (int)pw[2 * a][nf][1]);
        hi = __builtin_amdgcn_ds_bpermute(idxA, (int)pw[2 * a + 1][nf][1]);
        u[1] = (unsigned)(lowhalf ? lo : hi);
        lo = __builtin_amdgcn_ds_bpermute(idxB, (int)pw[2 * a][nf][0]);
        hi = __builtin_amdgcn_ds_bpermute(idxB, (int)pw[2 * a + 1][nf][0]);
        u[2] = (unsigned)(lowhalf ? lo : hi);
        lo = __builtin_amdgcn_ds_bpermute(idxB, (int)pw[2 * a][nf][1]);
        hi = __builtin_amdgcn_ds_bpermute(idxB, (int)pw[2 * a + 1][nf][1]);
        u[3] = (unsigned)(lowhalf ? lo : hi);
        pa[nf][a] = __builtin_bit_cast(short8v, u);
      }

    // ---------- O += P @ V ----------
#pragma unroll
    for (int a = 0; a < 2; ++a)
#pragma unroll
      for (int nd = 0; nd < 8; ++nd) {
        const int d = nd * 16 + qlane;
        const int kvr = a * 32 + g * 8;
        short8v vf = *(const short8v*)(ldsV + d * 128 + ((kvr * 2) ^ (((d ^ (d >> 2)) & 7) << 4)));
#pragma unroll
        for (int qf = 0; qf < 2; ++qf)
          oacc[qf][nd] = __builtin_amdgcn_mfma_f32_16x16x32_bf16(
              pa[qf][a], vf, oacc[qf][nd], 0, 0, 0);
      }
    __syncthreads();
  }

  // ---------- epilogue ----------
#pragma unroll
  for (int qf = 0; qf < 2; ++qf)
#pragma unroll
    for (int nd = 0; nd < 8; ++nd) {
#pragma unroll
      for (int r = 0; r < 4; ++r) {
        const int row = q0 + w * 32 + qf * 16 + g * 4 + r;
        Oh[(size_t)row * Ddim + nd * 16 + qlane] = oacc[qf][nd][r];
      }
    }
}

extern "C" void kernel_launch(void* const* d_in, const int* in_sizes, int n_in,
                              void* d_out, int out_size, void* d_ws, size_t ws_size,
                              hipStream_t stream) {
  (void)in_sizes; (void)n_in; (void)d_ws; (void)ws_size; (void)out_size;
  const float* q    = (const float*)d_in[0];
  const float* k    = (const float*)d_in[1];
  const float* v    = (const float*)d_in[2];
  const float* bias = (const float*)d_in[3];
  float* out = (float*)d_out;
  dim3 grid(384), block(256);
  hipLaunchKernelGGL(sigattn_kernel, grid, block, 0, stream, q, k, v, bias, out);
}

// Round 2
// 630.479 us; speedup vs baseline: 1.0029x; 1.0029x over previous
//
#include <hip/hip_runtime.h>

typedef __attribute__((ext_vector_type(4))) float f32x4;
typedef __attribute__((ext_vector_type(8))) short short8v;
typedef __attribute__((ext_vector_type(4))) unsigned int uint4v;

static constexpr int Sdim = 2048;
static constexpr int Ddim = 128;
static constexpr int BN   = 64;
static constexpr int NT   = Sdim / BN;   // 32
static constexpr float kAlpha0 = 0.08838834764831844f; // 1/sqrt(128)

__device__ __forceinline__ unsigned int bfpack(float a, float b) {
  unsigned int ua = __builtin_bit_cast(unsigned int, a);
  unsigned int ub = __builtin_bit_cast(unsigned int, b);
  ua = (ua + 0x7FFFu + ((ua >> 16) & 1u)) >> 16;
  ub = (ub + 0x7FFFu + ((ub >> 16) & 1u)) >> 16;
  return (ua & 0xFFFFu) | (ub << 16);
}
__device__ __forceinline__ unsigned short bf1(float a) {
  unsigned int ua = __builtin_bit_cast(unsigned int, a);
  return (unsigned short)((ua + 0x7FFFu + ((ua >> 16) & 1u)) >> 16);
}
__device__ __forceinline__ float fast_sigmoid(float x) {
  return __builtin_amdgcn_rcpf(1.0f + __expf(-x));
}
__device__ __forceinline__ void gll16(const void* g, void* l) {
  __builtin_amdgcn_global_load_lds(
      (const __attribute__((address_space(1))) unsigned int*)g,
      (__attribute__((address_space(3))) unsigned int*)l, 16, 0, 0);
}

// ---------- prepass: K fp32->bf16 straight; V fp32 -> V^T bf16 [head][d][S] ----------
__global__ __launch_bounds__(256) void prep_kernel(
    const float* __restrict__ K, const float* __restrict__ V,
    unsigned short* __restrict__ Kb, unsigned short* __restrict__ Vt) {
  __shared__ unsigned short ldsT[128 * 128];  // V^T tile, granule-swizzled
  const int head = blockIdx.x >> 4;
  const int tile = blockIdx.x & 15;           // 16 tiles of 128 kv rows
  const int t = threadIdx.x;
  const float* Kh = K + ((size_t)head * Sdim + tile * 128) * Ddim;
  const float* Vh = V + ((size_t)head * Sdim + tile * 128) * Ddim;
  unsigned short* Kbh = Kb + ((size_t)head * Sdim + tile * 128) * Ddim;
  unsigned short* Vth = Vt + (size_t)head * Ddim * Sdim + tile * 128;

  // K: cast-copy 128x128
#pragma unroll
  for (int c = 0; c < 8; ++c) {
    const int e8 = c * 256 + t;
    f32x4 a = *(const f32x4*)(Kh + e8 * 8);
    f32x4 b = *(const f32x4*)(Kh + e8 * 8 + 4);
    uint4v u;
    u[0] = bfpack(a[0], a[1]); u[1] = bfpack(a[2], a[3]);
    u[2] = bfpack(b[0], b[1]); u[3] = bfpack(b[2], b[3]);
    *(uint4v*)(Kbh + e8 * 8) = u;
  }
  // V: read [kv][d] coalesced, scatter-transpose into swizzled LDS [d][kv]
#pragma unroll
  for (int c = 0; c < 16; ++c) {
    const int e4 = c * 256 + t;
    const int kv = e4 >> 5;
    const int c4 = (e4 & 31) * 4;
    f32x4 v = *(const f32x4*)(Vh + (size_t)kv * Ddim + c4);
#pragma unroll
    for (int j = 0; j < 4; ++j) {
      const int d = c4 + j;
      const int sw = (d >> 2) & 7;
      ldsT[d * 128 + ((((kv >> 3) ^ sw) << 3) | (kv & 7))] = bf1(v[j]);
    }
  }
  __syncthreads();
  // read back rows (un-swizzle), write V^T global, plain layout
#pragma unroll
  for (int c = 0; c < 8; ++c) {
    const int G = c * 256 + t;
    const int d = G >> 4;
    const int s = G & 15;
    const int sw = (d >> 2) & 7;
    uint4v u = *(const uint4v*)(ldsT + d * 128 + ((s ^ sw) << 3));
    *(uint4v*)(Vth + (size_t)d * Sdim + s * 8) = u;
  }
}

// ---------- main: BM=64 (2 waves x 32 q-rows), BN=64, grid 768 = 3 blocks/CU ----------
__global__ __launch_bounds__(128, 2) void sigattn_kernel(
    const float* __restrict__ Q, const unsigned short* __restrict__ Kb,
    const unsigned short* __restrict__ Vt, const float* __restrict__ Bias,
    float* __restrict__ Out) {
  __shared__ __align__(16) unsigned char lds[3 * 16384]; // K:0..16K, V0:16K..32K, V1:32K..48K
  unsigned char* ldsK = lds;

  const int b    = blockIdx.x;
  const int xcd  = b & 7;
  const int jj   = b >> 3;                 // 0..95
  const int head = xcd * 3 + (jj >> 5);    // 24 heads, 3 per XCD
  const int q0   = (jj & 31) * 64;

  const int tid   = threadIdx.x;
  const int w     = tid >> 6;
  const int lane  = tid & 63;
  const int g     = lane >> 4;
  const int qlane = lane & 15;

  const float* Qh = Q + (size_t)head * Sdim * Ddim;
  const unsigned short* KbH = Kb + (size_t)head * Sdim * Ddim;
  const unsigned short* VtH = Vt + (size_t)head * Ddim * Sdim;
  const float* Bh = Bias + (size_t)head * Sdim * Sdim;
  float* Oh = Out + (size_t)head * Sdim * Ddim;

  // per-thread staging source offsets (pre-swizzled granules, rule #21)
  int koff[8], voff[8], dstb[8];
#pragma unroll
  for (int i = 0; i < 8; ++i) {
    const int G = i * 128 + w * 64 + lane;
    dstb[i] = (i * 128 + w * 64) * 16;          // wave-uniform LDS byte base
    const int kv = G >> 4, s = G & 15;
    koff[i] = kv * Ddim + ((s ^ (kv & 7)) << 3);           // halves within K tile
    const int d = G >> 3, s2 = G & 7;
    const int sw = (d ^ (d >> 2)) & 7;
    voff[i] = d * Sdim + ((s2 ^ sw) << 3);                 // halves; + kv0 per tile
  }

  // prologue: stage tile 0
#pragma unroll
  for (int i = 0; i < 8; ++i) gll16(KbH + koff[i], ldsK + dstb[i]);
#pragma unroll
  for (int i = 0; i < 8; ++i) gll16(VtH + voff[i], lds + 16384 + dstb[i]);

  // Q fragments (MFMA B operand) for the whole block, fp32 -> bf16 once
  short8v qfrag[2][4];
#pragma unroll
  for (int nf = 0; nf < 2; ++nf) {
    const float* qp = Qh + (size_t)(q0 + w * 32 + nf * 16 + qlane) * Ddim;
#pragma unroll
    for (int kf = 0; kf < 4; ++kf) {
      const int d0 = kf * 32 + g * 8;
      f32x4 a = *(const f32x4*)(qp + d0);
      f32x4 c = *(const f32x4*)(qp + d0 + 4);
      uint4v u;
      u[0] = bfpack(a[0], a[1]); u[1] = bfpack(a[2], a[3]);
      u[2] = bfpack(c[0], c[1]); u[3] = bfpack(c[2], c[3]);
      qfrag[nf][kf] = __builtin_bit_cast(short8v, u);
    }
  }

  const f32x4 fzero = {0.0f, 0.0f, 0.0f, 0.0f};
  f32x4 oacc[2][8];
#pragma unroll
  for (int qf = 0; qf < 2; ++qf)
#pragma unroll
    for (int nd = 0; nd < 8; ++nd) oacc[qf][nd] = fzero;

  const int idxA = ((((2 * g) & 3) * 16 + qlane) << 2);
  const int idxB = ((((2 * g + 1) & 3) * 16 + qlane) << 2);
  const bool lowhalf = (lane < 32);

  int buf = 0;
  for (int t = 0; t < NT; ++t) {
    const int kv0 = t * BN;
    __syncthreads();  // full drain: K/V tile t are in LDS for all waves

    // bias loads for tile t in S^T C/D layout (HBM stream, stays in flight past mid barrier)
    f32x4 bb[4][2];
#pragma unroll
    for (int mf = 0; mf < 4; ++mf)
#pragma unroll
      for (int nf = 0; nf < 2; ++nf) {
        const int row = q0 + w * 32 + nf * 16 + qlane;
        const int col = kv0 + mf * 16 + g * 4;
        bb[mf][nf] = *(const f32x4*)(Bh + (size_t)row * Sdim + col);
      }

    // S^T = K @ Q^T
    f32x4 sacc[4][2];
#pragma unroll
    for (int mf = 0; mf < 4; ++mf)
#pragma unroll
      for (int nf = 0; nf < 2; ++nf) sacc[mf][nf] = fzero;
#pragma unroll
    for (int kf = 0; kf < 4; ++kf)
#pragma unroll
      for (int mf = 0; mf < 4; ++mf) {
        const int kv = mf * 16 + qlane;
        const int d0 = kf * 32 + g * 8;
        short8v kf8 = *(const short8v*)(ldsK + kv * 256 + ((d0 * 2) ^ ((kv & 7) << 4)));
#pragma unroll
        for (int nf = 0; nf < 2; ++nf)
          sacc[mf][nf] = __builtin_amdgcn_mfma_f32_16x16x32_bf16(
              kf8, qfrag[nf][kf], sacc[mf][nf], 0, 0, 0);
      }

    // mid barrier: wait only LDS reads (keep bias DMA in flight), then barrier
    asm volatile("s_waitcnt lgkmcnt(0)" ::: "memory");
    __builtin_amdgcn_s_barrier();
    __builtin_amdgcn_sched_barrier(0);

    // stage tile t+1: K (buffer now free) + V into other buffer
    if (t + 1 < NT) {
      const int kvn = kv0 + BN;
#pragma unroll
      for (int i = 0; i < 8; ++i) gll16(KbH + kvn * Ddim + koff[i], ldsK + dstb[i]);
      unsigned char* vb1 = lds + 16384 + (buf ^ 1) * 16384;
#pragma unroll
      for (int i = 0; i < 8; ++i) gll16(VtH + kvn + voff[i], vb1 + dstb[i]);
    }

    // sigmoid(alpha0*S + bias) -> packed bf16 pairs
    unsigned int pw[4][2][2];
#pragma unroll
    for (int mf = 0; mf < 4; ++mf)
#pragma unroll
      for (int nf = 0; nf < 2; ++nf) {
        float p0 = fast_sigmoid(sacc[mf][nf][0] * kAlpha0 + bb[mf][nf][0]);
        float p1 = fast_sigmoid(sacc[mf][nf][1] * kAlpha0 + bb[mf][nf][1]);
        float p2 = fast_sigmoid(sacc[mf][nf][2] * kAlpha0 + bb[mf][nf][2]);
        float p3 = fast_sigmoid(sacc[mf][nf][3] * kAlpha0 + bb[mf][nf][3]);
        pw[mf][nf][0] = bfpack(p0, p1);
        pw[mf][nf][1] = bfpack(p2, p3);
      }

    // redistribute P^T (C/D layout) -> PV A-fragments (in-register, ds_bpermute)
    short8v pa[2][2];
#pragma unroll
    for (int nf = 0; nf < 2; ++nf)
#pragma unroll
      for (int a = 0; a < 2; ++a) {
        uint4v u;
        int lo, hi;
        lo = __builtin_amdgcn_ds_bpermute(idxA, (int)pw[2 * a][nf][0]);
        hi = __builtin_amdgcn_ds_bpermute(idxA, (int)pw[2 * a + 1][nf][0]);
        u[0] = (unsigned)(lowhalf ? lo : hi);
        lo = __builtin_amdgcn_ds_bpermute(idxA, (int)pw[2 * a][nf][1]);
        hi = __builtin_amdgcn_ds_bpermute(idxA, (int)pw[2 * a + 1][nf][1]);
        u[1] = (unsigned)(lowhalf ? lo : hi);
        lo = __builtin_amdgcn_ds_bpermute(idxB, (int)pw[2 * a][nf][0]);
        hi = __builtin_amdgcn_ds_bpermute(idxB, (int)pw[2 * a + 1][nf][0]);
        u[2] = (unsigned)(lowhalf ? lo : hi);
        lo = __builtin_amdgcn_ds_bpermute(idxB, (int)pw[2 * a][nf][1]);
        hi = __builtin_amdgcn_ds_bpermute(idxB, (int)pw[2 * a + 1][nf][1]);
        u[3] = (unsigned)(lowhalf ? lo : hi);
        pa[nf][a] = __builtin_bit_cast(short8v, u);
      }

    // O += P @ V   (V^T tile in LDS buffer `buf`)
    const unsigned char* vb = lds + 16384 + buf * 16384;
#pragma unroll
    for (int a = 0; a < 2; ++a)
#pragma unroll
      for (int nd = 0; nd < 8; ++nd) {
        const int d = nd * 16 + qlane;
        const int kvr = a * 32 + g * 8;
        const int sw = (d ^ (d >> 2)) & 7;
        short8v vf = *(const short8v*)(vb + d * 128 + ((kvr * 2) ^ (sw << 4)));
#pragma unroll
        for (int qf = 0; qf < 2; ++qf)
          oacc[qf][nd] = __builtin_amdgcn_mfma_f32_16x16x32_bf16(
              pa[qf][a], vf, oacc[qf][nd], 0, 0, 0);
      }
    buf ^= 1;
  }

  // epilogue
#pragma unroll
  for (int qf = 0; qf < 2; ++qf)
#pragma unroll
    for (int nd = 0; nd < 8; ++nd)
#pragma unroll
      for (int r = 0; r < 4; ++r) {
        const int row = q0 + w * 32 + qf * 16 + g * 4 + r;
        Oh[(size_t)row * Ddim + nd * 16 + qlane] = oacc[qf][nd][r];
      }
}

extern "C" void kernel_launch(void* const* d_in, const int* in_sizes, int n_in,
                              void* d_out, int out_size, void* d_ws, size_t ws_size,
                              hipStream_t stream) {
  (void)in_sizes; (void)n_in; (void)ws_size; (void)out_size;
  const float* q    = (const float*)d_in[0];
  const float* k    = (const float*)d_in[1];
  const float* v    = (const float*)d_in[2];
  const float* bias = (const float*)d_in[3];
  float* out = (float*)d_out;
  unsigned short* Kb = (unsigned short*)d_ws;
  unsigned short* Vt = Kb + (size_t)24 * Sdim * Ddim;

  hipLaunchKernelGGL(prep_kernel, dim3(384), dim3(256), 0, stream, k, v, Kb, Vt);
  hipLaunchKernelGGL(sigattn_kernel, dim3(768), dim3(128), 0, stream,
                     q, Kb, Vt, bias, out);
}